// Round 12
// baseline (228.041 us; speedup 1.0000x reference)
//
#include <hip/hip_runtime.h>
#include <hip/hip_fp16.h>

constexpr int N_NODES = 50000;
constexpr int N_EDGES = 800000;
constexpr int HIDDEN  = 128;
constexpr float RSQRT_D = 0.17677669529663687f;  // 1/sqrt(32)
constexpr int Y_SIZE = N_NODES * HIDDEN;         // 6,400,000
constexpr int M_PAD  = 50048;                    // 391 * 128
constexpr int MM_BLOCKS = M_PAD / 128;           // 391
constexpr int SCAN_BLOCKS = 196;                 // 196*256 = 50176 >= N_NODES
constexpr int XCVT_BLOCKS = (M_PAD * 16) / 256;  // 3128
constexpr int HIST_BLOCKS = N_EDGES / 256;       // 3125
constexpr int STAT_BLOCKS = (N_NODES + 31) / 32; // 1563
constexpr int EX_CAP = 128;                      // per-node LDS ex slots (deg>128 -> global)

// ---- ws layout (float offsets) ----
constexpr size_t OFF_Q      = 0;         // fp16 qb
constexpr size_t OFF_K      = 6400000;   // fp16 kv interleaved [node][256]: 25.6 MB
constexpr size_t OFF_S      = 19200000;  // fp16 sb
constexpr size_t OFF_EXC    = 22400000;  // E*4 floats: overflow fallback only
constexpr size_t OFF_WT     = 25600000;  // Wt_swz bf16 (dead after k_mm)
constexpr size_t OFF_GSUM   = 25800000;  // 64
constexpr size_t OFF_GSQ    = 25800064;  // 64
constexpr size_t OFF_GCNT   = 25800128;  // 64 ints
constexpr size_t OFF_DEG    = 25800192;  // 50000 ints
constexpr size_t OFF_OFFS   = 25850192;  // 50001 ints
constexpr size_t OFF_CURSOR = 25900224;  // 50000 ints
constexpr size_t OFF_CSR    = 25950224;  // 800000 int2 (packed src,eid)
constexpr size_t OFF_PART   = 27550224;  // 196 ints (raw scan partials)

typedef __attribute__((ext_vector_type(8))) short bf16x8;
typedef __attribute__((ext_vector_type(4))) float f32x4;

__device__ __forceinline__ short f2bf(float f) {  // RNE f32 -> bf16 bits
    unsigned u = __float_as_uint(f);
    unsigned r = (u + 0x7fff + ((u >> 16) & 1)) >> 16;
    return (short)r;
}

__device__ __forceinline__ void gload_lds16(const void* g, void* l) {
    __builtin_amdgcn_global_load_lds(
        (const __attribute__((address_space(1))) void*)g,
        (__attribute__((address_space(3))) void*)l, 16, 0, 0);
}

// ---------------- prep: x->bf16 swizzled | W->Wt bf16 swizzled | degree hist ----------------
__global__ __launch_bounds__(256) void k_prep(
    const float* __restrict__ x,
    const float* __restrict__ Wq, const float* __restrict__ Wk,
    const float* __restrict__ Wv, const float* __restrict__ Wsm,
    const int* __restrict__ dst,
    short* __restrict__ xs, short* __restrict__ wt, int* __restrict__ deg)
{
    int b = blockIdx.x;
    if (b < XCVT_BLOCKS) {
        int tid = b * 256 + threadIdx.x;  // M_PAD*16 exact
        int row = tid >> 4, ci = tid & 15;
        short o[8];
        if (row < N_NODES) {
            float4 a = *(const float4*)&x[(size_t)row * 128 + ci * 8];
            float4 bb = *(const float4*)&x[(size_t)row * 128 + ci * 8 + 4];
            o[0] = f2bf(a.x); o[1] = f2bf(a.y); o[2] = f2bf(a.z); o[3] = f2bf(a.w);
            o[4] = f2bf(bb.x); o[5] = f2bf(bb.y); o[6] = f2bf(bb.z); o[7] = f2bf(bb.w);
        } else {
            #pragma unroll
            for (int j = 0; j < 8; ++j) o[j] = 0;
        }
        int cs = ci ^ (row & 7);
        *(int4*)&xs[(size_t)row * 128 + cs * 8] = *(int4*)o;
    } else if (b < XCVT_BLOCKS + 32) {
        int tid = (b - XCVT_BLOCKS) * 256 + threadIdx.x;  // 8192 exact
        int mat = tid >> 11, n = (tid >> 4) & 127, kg = tid & 15;
        const float* W = (mat == 0) ? Wq : (mat == 1) ? Wk : (mat == 2) ? Wv : Wsm;
        short o[8];
        #pragma unroll
        for (int j = 0; j < 8; ++j) o[j] = f2bf(W[(kg * 8 + j) * 128 + n]);
        int cs = kg ^ (n & 7);
        *(int4*)&wt[mat * 16384 + n * 128 + cs * 8] = *(int4*)o;
    } else {
        int e = (b - XCVT_BLOCKS - 32) * 256 + threadIdx.x;  // E exact
        atomicAdd(&deg[dst[e]], 1);
    }
}

// ---------------- merged: MFMA GEMM (4 mats) | scan phase 1 ----------------
__global__ __launch_bounds__(256) void k_mmscan(
    const short* __restrict__ xs, const short* __restrict__ wt,
    const float* __restrict__ bq, const float* __restrict__ bk,
    const float* __restrict__ bv, const float* __restrict__ bs,
    __half* __restrict__ qb, __half* __restrict__ kv, __half* __restrict__ sb,
    const int* __restrict__ deg, int* __restrict__ part)
{
    if (blockIdx.x >= MM_BLOCKS) {  // ---- scan1 path ----
        const int t = threadIdx.x;
        int idx = (blockIdx.x - MM_BLOCKS) * 256 + t;
        int v = (idx < N_NODES) ? deg[idx] : 0;
        #pragma unroll
        for (int o = 1; o < 64; o <<= 1) v += __shfl_xor(v, o);
        __shared__ int wsum1[4];
        if ((t & 63) == 0) wsum1[t >> 6] = v;
        __syncthreads();
        if (t == 0) part[blockIdx.x - MM_BLOCKS] = wsum1[0] + wsum1[1] + wsum1[2] + wsum1[3];
        return;
    }
    // ---- GEMM path ----
    __shared__ __align__(16) char As[32768];
    __shared__ __align__(16) char Bs[32768];
    const int t = threadIdx.x, lane = t & 63, wv = t >> 6;
    const int m0 = blockIdx.x * 128;
    const int wm = wv >> 1, wn = wv & 1;

    const char* gA = (const char*)xs + (size_t)m0 * 256;
    #pragma unroll
    for (int i = 0; i < 8; ++i) {
        int chunk = wv * 8 + i;
        gload_lds16(gA + chunk * 1024 + lane * 16, As + chunk * 1024);
        gload_lds16((const char*)wt + chunk * 1024 + lane * 16, Bs + chunk * 1024);
    }
    __syncthreads();

    bf16x8 af[4][4];  // [ks][mf], same A for all mats
    #pragma unroll
    for (int ks = 0; ks < 4; ++ks) {
        const int cbase = ks * 64 + ((lane >> 4) << 4);
        #pragma unroll
        for (int mf = 0; mf < 4; ++mf) {
            int mr = wm * 64 + mf * 16 + (lane & 15);
            af[ks][mf] = *(const bf16x8*)(As + mr * 256 + (cbase ^ ((mr & 7) << 4)));
        }
    }

    const float* Bbs[4] = {bq, bk, bv, bs};
    #pragma unroll
    for (int mat = 0; mat < 4; ++mat) {
        f32x4 acc[4][4];
        #pragma unroll
        for (int nf = 0; nf < 4; ++nf) {
            float bc = Bbs[mat][wn * 64 + nf * 16 + (lane & 15)];
            #pragma unroll
            for (int mf = 0; mf < 4; ++mf) acc[mf][nf] = (f32x4){bc, bc, bc, bc};
        }
        #pragma unroll
        for (int ks = 0; ks < 4; ++ks) {
            bf16x8 bfr[4];
            const int cbase = ks * 64 + ((lane >> 4) << 4);
            #pragma unroll
            for (int nf = 0; nf < 4; ++nf) {
                int nc = wn * 64 + nf * 16 + (lane & 15);
                bfr[nf] = *(const bf16x8*)(Bs + nc * 256 + (cbase ^ ((nc & 7) << 4)));
            }
            #pragma unroll
            for (int mf = 0; mf < 4; ++mf)
                #pragma unroll
                for (int nf = 0; nf < 4; ++nf)
                    acc[mf][nf] = __builtin_amdgcn_mfma_f32_16x16x32_bf16(
                        af[ks][mf], bfr[nf], acc[mf][nf], 0, 0, 0);
        }
        __syncthreads();  // all waves done reading Bs
        if (mat < 3) {    // stage next mat's B while we write out
            const char* gB = (const char*)wt + (mat + 1) * 32768;
            #pragma unroll
            for (int i = 0; i < 8; ++i) {
                int chunk = wv * 8 + i;
                gload_lds16(gB + chunk * 1024 + lane * 16, Bs + chunk * 1024);
            }
        }
        __half* base = (mat == 0) ? qb : (mat == 1) ? kv : (mat == 2) ? (kv + 128) : sb;
        const int rs = (mat == 1 || mat == 2) ? 256 : 128;
        const int colbase = wn * 64 + (lane & 15);
        #pragma unroll
        for (int mf = 0; mf < 4; ++mf) {
            int rowb = m0 + wm * 64 + mf * 16 + ((lane >> 4) << 2);
            #pragma unroll
            for (int nf = 0; nf < 4; ++nf) {
                int col = colbase + nf * 16;
                #pragma unroll
                for (int r = 0; r < 4; ++r) {
                    int node = rowb + r;
                    if (node < N_NODES)
                        base[(size_t)node * rs + col] = __float2half_rn(acc[mf][nf][r]);
                }
            }
        }
        __syncthreads();  // staged Bs complete before next mat's reads
    }
}

// ---------------- scan3: redundant partial-scan + intra-block scan ----------------
__global__ __launch_bounds__(256) void k_scan3(const int* __restrict__ deg,
                                               const int* __restrict__ part,
                                               int* __restrict__ offs,
                                               int* __restrict__ cursor)
{
    __shared__ int pbuf[256];
    __shared__ int wsum[4];
    const int t = threadIdx.x;
    int pv = (t < SCAN_BLOCKS) ? part[t] : 0;
    pbuf[t] = pv;
    __syncthreads();
    for (int o = 1; o < 256; o <<= 1) {
        int tmp = (t >= o) ? pbuf[t - o] : 0;
        __syncthreads();
        pbuf[t] += tmp;
        __syncthreads();
    }
    const int bbase = (blockIdx.x == 0) ? 0 : pbuf[blockIdx.x - 1];

    const int idx = blockIdx.x * 256 + t;
    const int lane = t & 63, w = t >> 6;
    int v = (idx < N_NODES) ? deg[idx] : 0;
    int inc = v;
    #pragma unroll
    for (int o = 1; o < 64; o <<= 1) {
        int nb = __shfl_up(inc, o);
        if (lane >= o) inc += nb;
    }
    if (lane == 63) wsum[w] = inc;
    __syncthreads();
    int wbase = 0;
    #pragma unroll
    for (int i = 0; i < 4; ++i) if (i < w) wbase += wsum[i];
    int excl = bbase + wbase + inc - v;
    if (idx < N_NODES) {
        offs[idx] = excl;
        cursor[idx] = excl;
    }
    if (idx == 0) offs[N_NODES] = N_EDGES;
}

__global__ __launch_bounds__(256) void k_scatter(
    const int* __restrict__ src, const int* __restrict__ dst,
    int* __restrict__ cursor, int2* __restrict__ csr)
{
    int e = blockIdx.x * 256 + threadIdx.x;  // E exact
    int d = dst[e];
    int p = atomicAdd(&cursor[d], 1);
    csr[p] = make_int2(src[e], e);
}

// ---------------- fused: logits + exp + aggregate + skip + attn normalize ----------------
// One 64-lane wave per dst node; 16 lanes/edge (8 ch/lane), 4 edges per group.
// 2-stage software pipeline (prefetch next group while computing current).
// ex stashed in LDS (EX_CAP slots/node; global exc fallback for deg>EX_CAP).
#define GRP_COMPUTE(BASE, K0, K1, K2, K3, V0, V1, V2, V3)                     \
    {                                                                         \
        float2 f0 = __half22float2(K0), f1 = __half22float2(K1),              \
               f2 = __half22float2(K2), f3 = __half22float2(K3);              \
        float p = qf[0].x*f0.x + qf[0].y*f0.y + qf[1].x*f1.x + qf[1].y*f1.y   \
                + qf[2].x*f2.x + qf[2].y*f2.y + qf[3].x*f3.x + qf[3].y*f3.y;  \
        p += __shfl_xor(p, 1);                                                \
        p += __shfl_xor(p, 2);                                                \
        const float ex = __expf(p * RSQRT_D);                                 \
        dsum += ex;                                                           \
        float2 g0 = __half22float2(V0), g1 = __half22float2(V1),              \
               g2 = __half22float2(V2), g3 = __half22float2(V3);              \
        acc[0] += ex * g0.x; acc[1] += ex * g0.y;                             \
        acc[2] += ex * g1.x; acc[3] += ex * g1.y;                             \
        acc[4] += ex * g2.x; acc[5] += ex * g2.y;                             \
        acc[6] += ex * g3.x; acc[7] += ex * g3.y;                             \
        if ((lane & 3) == 0) {                                                \
            int sl = (BASE) + qtr - begin;                                    \
            if (sl < EX_CAP) exs[nl][sl * 4 + h] = ex;                        \
            else             exc[((size_t)((BASE) + qtr)) * 4 + h] = ex;      \
        }                                                                     \
    }

__global__ __launch_bounds__(256) void k_fused(
    const __half* __restrict__ qb, const __half* __restrict__ kv,
    const __half* __restrict__ sb,
    const int* __restrict__ offs, const int2* __restrict__ csr,
    float* __restrict__ exc, float* __restrict__ attn,
    float* __restrict__ outb)
{
    __shared__ __align__(16) float exs[4][EX_CAP * 4];  // 8 KB
    const int t = threadIdx.x;
    const int lane = t & 63;
    const int nl = t >> 6;
    const int n = blockIdx.x * 4 + nl;  // grid*4 == N exact
    const int begin = offs[n], end = offs[n + 1];
    const int cl  = lane & 15;   // owns channels [cl*8, cl*8+8)
    const int qtr = lane >> 4;   // edge slot within 4-group
    const int h   = cl >> 2;     // head of this lane's channels

    const __half2* qp = (const __half2*)(qb + (size_t)n * 128 + cl * 8);
    float2 qf[4];
    #pragma unroll
    for (int j = 0; j < 4; ++j) qf[j] = __half22float2(qp[j]);

    float acc[8] = {0.f, 0.f, 0.f, 0.f, 0.f, 0.f, 0.f, 0.f};
    float dsum = 0.f;
    int i = begin;

    if (i + 4 <= end) {
        // preload group 0
        const __half2* kpC = (const __half2*)(kv + (size_t)csr[i + qtr].x * 256 + cl * 8);
        __half2 kC0 = kpC[0],  kC1 = kpC[1],  kC2 = kpC[2],  kC3 = kpC[3];
        __half2 vC0 = kpC[64], vC1 = kpC[65], vC2 = kpC[66], vC3 = kpC[67];
        while (i + 8 <= end) {
            // prefetch next group
            const __half2* kpN = (const __half2*)(kv + (size_t)csr[i + 4 + qtr].x * 256 + cl * 8);
            __half2 kN0 = kpN[0],  kN1 = kpN[1],  kN2 = kpN[2],  kN3 = kpN[3];
            __half2 vN0 = kpN[64], vN1 = kpN[65], vN2 = kpN[66], vN3 = kpN[67];
            GRP_COMPUTE(i, kC0, kC1, kC2, kC3, vC0, vC1, vC2, vC3);
            kC0 = kN0; kC1 = kN1; kC2 = kN2; kC3 = kN3;
            vC0 = vN0; vC1 = vN1; vC2 = vN2; vC3 = vN3;
            i += 4;
        }
        GRP_COMPUTE(i, kC0, kC1, kC2, kC3, vC0, vC1, vC2, vC3);
        i += 4;
    }
    if (i < end) {  // guarded tail: 1-3 edges
        const int eIdx = i + qtr;
        const bool act = eIdx < end;
        const __half2* kp = (const __half2*)(kv + (size_t)csr[act ? eIdx : end - 1].x * 256 + cl * 8);
        __half2 ka0 = kp[0],  ka1 = kp[1],  ka2 = kp[2],  ka3 = kp[3];
        __half2 va0 = kp[64], va1 = kp[65], va2 = kp[66], va3 = kp[67];
        float2 f0 = __half22float2(ka0), f1 = __half22float2(ka1),
               f2 = __half22float2(ka2), f3 = __half22float2(ka3);
        float p = qf[0].x*f0.x + qf[0].y*f0.y + qf[1].x*f1.x + qf[1].y*f1.y
                + qf[2].x*f2.x + qf[2].y*f2.y + qf[3].x*f3.x + qf[3].y*f3.y;
        p += __shfl_xor(p, 1);
        p += __shfl_xor(p, 2);
        const float ex = act ? __expf(p * RSQRT_D) : 0.f;
        dsum += ex;
        float2 g0 = __half22float2(va0), g1 = __half22float2(va1),
               g2 = __half22float2(va2), g3 = __half22float2(va3);
        acc[0] += ex * g0.x; acc[1] += ex * g0.y;
        acc[2] += ex * g1.x; acc[3] += ex * g1.y;
        acc[4] += ex * g2.x; acc[5] += ex * g2.y;
        acc[6] += ex * g3.x; acc[7] += ex * g3.y;
        if (((lane & 3) == 0) && act) {
            int sl = eIdx - begin;
            if (sl < EX_CAP) exs[nl][sl * 4 + h] = ex;
            else             exc[(size_t)eIdx * 4 + h] = ex;
        }
    }

    // combine the 4 edge-quarters (lanes l, l+16, l+32, l+48 share channels)
    dsum += __shfl_xor(dsum, 16);
    dsum += __shfl_xor(dsum, 32);
    #pragma unroll
    for (int j = 0; j < 8; ++j) {
        acc[j] += __shfl_xor(acc[j], 16);
        acc[j] += __shfl_xor(acc[j], 32);
    }
    // per-head reciprocal denominators, broadcast to every lane
    const float rd0 = 1.f / (__shfl(dsum, 0)  + 1e-16f);
    const float rd1 = 1.f / (__shfl(dsum, 4)  + 1e-16f);
    const float rd2 = 1.f / (__shfl(dsum, 8)  + 1e-16f);
    const float rd3 = 1.f / (__shfl(dsum, 12) + 1e-16f);

    if (lane < 16) {
        const float rdn = 1.f / (dsum + 1e-16f);
        const __half2* sp = (const __half2*)(sb + (size_t)n * 128 + cl * 8);
        float o[8];
        #pragma unroll
        for (int j = 0; j < 4; ++j) {
            float2 sf = __half22float2(sp[j]);
            o[2*j]   = acc[2*j]   * rdn + sf.x;
            o[2*j+1] = acc[2*j+1] * rdn + sf.y;
        }
        *(float4*)&outb[(size_t)n * 128 + cl * 8]     = make_float4(o[0], o[1], o[2], o[3]);
        *(float4*)&outb[(size_t)n * 128 + cl * 8 + 4] = make_float4(o[4], o[5], o[6], o[7]);
    }

    __builtin_amdgcn_sched_barrier(0);  // keep LDS stash writes before epilogue reads

    // normalize this node's attn slots: 1 edge/lane, gathered 16B random write
    for (int slot = begin + lane; slot < end; slot += 64) {
        const int eid = csr[slot].y;
        const int sl = slot - begin;
        float4 e4 = (sl < EX_CAP) ? *(const float4*)&exs[nl][sl * 4]
                                  : *(const float4*)&exc[(size_t)slot * 4];
        ((float4*)attn)[eid] = make_float4(e4.x * rd0, e4.y * rd1,
                                           e4.z * rd2, e4.w * rd3);
    }
}

// ---------------- per-graph sum + sumsq + count, one pass ----------------
__global__ __launch_bounds__(256) void k_stats(
    const float* __restrict__ out, const int* __restrict__ batch,
    float* __restrict__ gsum, float* __restrict__ gsq, int* __restrict__ gcnt)
{
    __shared__ float nsum[32], nsq[32];
    __shared__ int   ngr[32];
    const int t = threadIdx.x;
    const int nl = t >> 3, part = t & 7;
    const int n = blockIdx.x * 32 + nl;
    float lsum = 0.f, lsq = 0.f;
    if (n < N_NODES) {
        size_t base = (size_t)n * 128 + part * 16;
        #pragma unroll
        for (int i = 0; i < 4; ++i) {
            float4 o = *(const float4*)&out[base + i * 4];
            lsum += o.x + o.y + o.z + o.w;
            lsq  += o.x * o.x + o.y * o.y + o.z * o.z + o.w * o.w;
        }
    }
    #pragma unroll
    for (int o = 1; o < 8; o <<= 1) {
        lsum += __shfl_xor(lsum, o);
        lsq  += __shfl_xor(lsq, o);
    }
    if (part == 0) { nsum[nl] = lsum; nsq[nl] = lsq; ngr[nl] = (n < N_NODES) ? batch[n] : -1; }
    __syncthreads();
    if (t == 0) {
        float acc = 0.f, accq = 0.f; int cg = ngr[0], cnt = 0;
        for (int i = 0; i < 32; ++i) {
            int g = ngr[i];
            if (g != cg) {
                if (cg >= 0) { atomicAdd(&gsum[cg], acc); atomicAdd(&gsq[cg], accq);
                               atomicAdd(&gcnt[cg], cnt); }
                acc = 0.f; accq = 0.f; cnt = 0; cg = g;
            }
            acc += nsum[i]; accq += nsq[i]; ++cnt;
        }
        if (cg >= 0) { atomicAdd(&gsum[cg], acc); atomicAdd(&gsq[cg], accq);
                       atomicAdd(&gcnt[cg], cnt); }
    }
}

// ---------------- LayerNorm affine + LeakyReLU (in-place) ----------------
__global__ __launch_bounds__(256) void k_final(
    const float* __restrict__ out, const int* __restrict__ batch,
    const float* __restrict__ gsum, const float* __restrict__ gsq,
    const int* __restrict__ gcnt,
    const float* __restrict__ lnw, const float* __restrict__ lnb,
    float* __restrict__ y)
{
    int idx = blockIdx.x * 256 + threadIdx.x;  // N*128 exact
    int n = idx >> 7, c = idx & 127;
    int g = batch[n];
    float norm = fmaxf((float)gcnt[g], 1.f) * 128.f;
    float mean = gsum[g] / norm;
    float var  = gsq[g] / norm - mean * mean;
    float inv  = rsqrtf(var + 1e-5f);
    float val  = (out[idx] - mean) * inv * lnw[c] + lnb[c];
    y[idx] = val > 0.f ? val : 0.01f * val;
}

extern "C" void kernel_launch(void* const* d_in, const int* in_sizes, int n_in,
                              void* d_out, int out_size, void* d_ws, size_t ws_size,
                              hipStream_t stream)
{
    (void)in_sizes; (void)n_in; (void)out_size; (void)ws_size;
    const float* x    = (const float*)d_in[0];
    const int*   ei   = (const int*)  d_in[1];
    const int*   batch= (const int*)  d_in[2];
    const float* Wq   = (const float*)d_in[3];
    const float* bq   = (const float*)d_in[4];
    const float* Wk   = (const float*)d_in[5];
    const float* bk   = (const float*)d_in[6];
    const float* Wv   = (const float*)d_in[7];
    const float* bv   = (const float*)d_in[8];
    const float* Wsm  = (const float*)d_in[9];
    const float* bs   = (const float*)d_in[10];
    const float* lnw  = (const float*)d_in[11];
    const float* lnb  = (const float*)d_in[12];

    float* outp = (float*)d_out;
    float* ws   = (float*)d_ws;

    const int* srcI = ei;
    const int* dstI = ei + N_EDGES;

    __half* qb      = (__half*)(ws + OFF_Q);
    __half* kv      = (__half*)(ws + OFF_K);
    __half* sb      = (__half*)(ws + OFF_S);
    float*  exc     = ws + OFF_EXC;
    short*  wt      = (short*)(ws + OFF_WT);
    float*  gsum    = ws + OFF_GSUM;
    float*  gsq     = ws + OFF_GSQ;
    int*    gcnt    = (int*)(ws + OFF_GCNT);
    int*    deg     = (int*)(ws + OFF_DEG);
    int*    offs    = (int*)(ws + OFF_OFFS);
    int*    cursor  = (int*)(ws + OFF_CURSOR);
    int2*   csr     = (int2*)(ws + OFF_CSR);
    int*    partArr = (int*)(ws + OFF_PART);

    float* outb  = outp;                  // y region: x_swz first, then pre-LN out
    short* x_swz = (short*)outp;          // 12.8 MB, dead once k_mmscan finishes
    float* attn  = outp + Y_SIZE;

    // zero gsum/gsq/gcnt + deg (contiguous)
    hipMemsetAsync(gsum, 0, (size_t)(192 + N_NODES) * sizeof(float), stream);

    k_prep<<<XCVT_BLOCKS + 32 + HIST_BLOCKS, 256, 0, stream>>>(
        x, Wq, Wk, Wv, Wsm, dstI, x_swz, wt, deg);
    k_mmscan<<<MM_BLOCKS + SCAN_BLOCKS, 256, 0, stream>>>(
        x_swz, wt, bq, bk, bv, bs, qb, kv, sb, deg, partArr);
    k_scan3<<<SCAN_BLOCKS, 256, 0, stream>>>(deg, partArr, offs, cursor);
    k_scatter<<<N_EDGES / 256, 256, 0, stream>>>(srcI, dstI, cursor, csr);
    k_fused<<<N_NODES / 4, 256, 0, stream>>>(qb, kv, sb, offs, csr,
                                             exc, attn, outb);
    k_stats<<<STAT_BLOCKS, 256, 0, stream>>>(outb, batch, gsum, gsq, gcnt);
    k_final<<<Y_SIZE / 256, 256, 0, stream>>>(outb, batch, gsum, gsq, gcnt,
                                              lnw, lnb, outp);
}

// Round 13
// 224.380 us; speedup vs baseline: 1.0163x; 1.0163x over previous
//
#include <hip/hip_runtime.h>
#include <hip/hip_fp16.h>

constexpr int N_NODES = 50000;
constexpr int N_EDGES = 800000;
constexpr int HIDDEN  = 128;
constexpr float RSQRT_D = 0.17677669529663687f;  // 1/sqrt(32)
constexpr int Y_SIZE = N_NODES * HIDDEN;         // 6,400,000
constexpr int M_PAD  = 50048;                    // 391 * 128
constexpr int MM_BLOCKS = M_PAD / 128;           // 391
constexpr int SCAN_BLOCKS = 196;                 // 196*256 = 50176 >= N_NODES
constexpr int XCVT_BLOCKS = (M_PAD * 16) / 256;  // 3128
constexpr int HIST_BLOCKS = N_EDGES / 256;       // 3125
constexpr int EX_CAP = 128;                      // per-node LDS ex slots (deg>128 -> global)

// ---- ws layout (float offsets) ----
constexpr size_t OFF_Q      = 0;         // fp16 qb
constexpr size_t OFF_K      = 6400000;   // fp16 kv interleaved [node][256]: 25.6 MB
constexpr size_t OFF_S      = 19200000;  // fp16 sb
constexpr size_t OFF_EXC    = 22400000;  // E*4 floats: overflow fallback only
constexpr size_t OFF_WT     = 25600000;  // Wt_swz bf16 (dead after k_mm)
constexpr size_t OFF_GSUM   = 25800000;  // 64
constexpr size_t OFF_GSQ    = 25800064;  // 64
constexpr size_t OFF_GCNT   = 25800128;  // 64 ints
constexpr size_t OFF_DEG    = 25800192;  // 50000 ints
constexpr size_t OFF_OFFS   = 25850192;  // 50001 ints
constexpr size_t OFF_CURSOR = 25900224;  // 50000 ints
constexpr size_t OFF_CSR    = 25950224;  // 800000 int2 (packed src,eid)
constexpr size_t OFF_PART   = 27550224;  // 196 ints (raw scan partials)
constexpr size_t OFF_NSTAT  = 27550420;  // 50000 float2 (per-node sum, sumsq)

typedef __attribute__((ext_vector_type(8))) short bf16x8;
typedef __attribute__((ext_vector_type(4))) float f32x4;
typedef __attribute__((ext_vector_type(2))) _Float16 h2;

#if defined(__has_builtin)
# if __has_builtin(__builtin_amdgcn_fdot2)
#  define HAS_FDOT2 1
# endif
#endif

__device__ __forceinline__ float dot8(h2 a0, h2 a1, h2 a2, h2 a3,
                                      h2 b0, h2 b1, h2 b2, h2 b3)
{
#ifdef HAS_FDOT2
    float p = __builtin_amdgcn_fdot2(a0, b0, 0.f, false);
    p = __builtin_amdgcn_fdot2(a1, b1, p, false);
    p = __builtin_amdgcn_fdot2(a2, b2, p, false);
    p = __builtin_amdgcn_fdot2(a3, b3, p, false);
    return p;
#else
    float p = 0.f;
    p += (float)a0.x * (float)b0.x + (float)a0.y * (float)b0.y;
    p += (float)a1.x * (float)b1.x + (float)a1.y * (float)b1.y;
    p += (float)a2.x * (float)b2.x + (float)a2.y * (float)b2.y;
    p += (float)a3.x * (float)b3.x + (float)a3.y * (float)b3.y;
    return p;
#endif
}

__device__ __forceinline__ short f2bf(float f) {  // RNE f32 -> bf16 bits
    unsigned u = __float_as_uint(f);
    unsigned r = (u + 0x7fff + ((u >> 16) & 1)) >> 16;
    return (short)r;
}

__device__ __forceinline__ void gload_lds16(const void* g, void* l) {
    __builtin_amdgcn_global_load_lds(
        (const __attribute__((address_space(1))) void*)g,
        (__attribute__((address_space(3))) void*)l, 16, 0, 0);
}

// ---------------- prep: x->bf16 swizzled | W->Wt bf16 swizzled | degree hist ----------------
__global__ __launch_bounds__(256) void k_prep(
    const float* __restrict__ x,
    const float* __restrict__ Wq, const float* __restrict__ Wk,
    const float* __restrict__ Wv, const float* __restrict__ Wsm,
    const int* __restrict__ dst,
    short* __restrict__ xs, short* __restrict__ wt, int* __restrict__ deg)
{
    int b = blockIdx.x;
    if (b < XCVT_BLOCKS) {
        int tid = b * 256 + threadIdx.x;  // M_PAD*16 exact
        int row = tid >> 4, ci = tid & 15;
        short o[8];
        if (row < N_NODES) {
            float4 a = *(const float4*)&x[(size_t)row * 128 + ci * 8];
            float4 bb = *(const float4*)&x[(size_t)row * 128 + ci * 8 + 4];
            o[0] = f2bf(a.x); o[1] = f2bf(a.y); o[2] = f2bf(a.z); o[3] = f2bf(a.w);
            o[4] = f2bf(bb.x); o[5] = f2bf(bb.y); o[6] = f2bf(bb.z); o[7] = f2bf(bb.w);
        } else {
            #pragma unroll
            for (int j = 0; j < 8; ++j) o[j] = 0;
        }
        int cs = ci ^ (row & 7);
        *(int4*)&xs[(size_t)row * 128 + cs * 8] = *(int4*)o;
    } else if (b < XCVT_BLOCKS + 32) {
        int tid = (b - XCVT_BLOCKS) * 256 + threadIdx.x;  // 8192 exact
        int mat = tid >> 11, n = (tid >> 4) & 127, kg = tid & 15;
        const float* W = (mat == 0) ? Wq : (mat == 1) ? Wk : (mat == 2) ? Wv : Wsm;
        short o[8];
        #pragma unroll
        for (int j = 0; j < 8; ++j) o[j] = f2bf(W[(kg * 8 + j) * 128 + n]);
        int cs = kg ^ (n & 7);
        *(int4*)&wt[mat * 16384 + n * 128 + cs * 8] = *(int4*)o;
    } else {
        int e = (b - XCVT_BLOCKS - 32) * 256 + threadIdx.x;  // E exact
        atomicAdd(&deg[dst[e]], 1);
    }
}

// ---------------- merged: MFMA GEMM (4 mats) | scan phase 1 ----------------
__global__ __launch_bounds__(256) void k_mmscan(
    const short* __restrict__ xs, const short* __restrict__ wt,
    const float* __restrict__ bq, const float* __restrict__ bk,
    const float* __restrict__ bv, const float* __restrict__ bs,
    __half* __restrict__ qb, __half* __restrict__ kv, __half* __restrict__ sb,
    const int* __restrict__ deg, int* __restrict__ part)
{
    if (blockIdx.x >= MM_BLOCKS) {  // ---- scan1 path ----
        const int t = threadIdx.x;
        int idx = (blockIdx.x - MM_BLOCKS) * 256 + t;
        int v = (idx < N_NODES) ? deg[idx] : 0;
        #pragma unroll
        for (int o = 1; o < 64; o <<= 1) v += __shfl_xor(v, o);
        __shared__ int wsum1[4];
        if ((t & 63) == 0) wsum1[t >> 6] = v;
        __syncthreads();
        if (t == 0) part[blockIdx.x - MM_BLOCKS] = wsum1[0] + wsum1[1] + wsum1[2] + wsum1[3];
        return;
    }
    // ---- GEMM path ----
    __shared__ __align__(16) char As[32768];
    __shared__ __align__(16) char Bs[32768];
    const int t = threadIdx.x, lane = t & 63, wv = t >> 6;
    const int m0 = blockIdx.x * 128;
    const int wm = wv >> 1, wn = wv & 1;

    const char* gA = (const char*)xs + (size_t)m0 * 256;
    #pragma unroll
    for (int i = 0; i < 8; ++i) {
        int chunk = wv * 8 + i;
        gload_lds16(gA + chunk * 1024 + lane * 16, As + chunk * 1024);
        gload_lds16((const char*)wt + chunk * 1024 + lane * 16, Bs + chunk * 1024);
    }
    __syncthreads();

    bf16x8 af[4][4];  // [ks][mf], same A for all mats
    #pragma unroll
    for (int ks = 0; ks < 4; ++ks) {
        const int cbase = ks * 64 + ((lane >> 4) << 4);
        #pragma unroll
        for (int mf = 0; mf < 4; ++mf) {
            int mr = wm * 64 + mf * 16 + (lane & 15);
            af[ks][mf] = *(const bf16x8*)(As + mr * 256 + (cbase ^ ((mr & 7) << 4)));
        }
    }

    const float* Bbs[4] = {bq, bk, bv, bs};
    #pragma unroll
    for (int mat = 0; mat < 4; ++mat) {
        f32x4 acc[4][4];
        #pragma unroll
        for (int nf = 0; nf < 4; ++nf) {
            float bc = Bbs[mat][wn * 64 + nf * 16 + (lane & 15)];
            #pragma unroll
            for (int mf = 0; mf < 4; ++mf) acc[mf][nf] = (f32x4){bc, bc, bc, bc};
        }
        #pragma unroll
        for (int ks = 0; ks < 4; ++ks) {
            bf16x8 bfr[4];
            const int cbase = ks * 64 + ((lane >> 4) << 4);
            #pragma unroll
            for (int nf = 0; nf < 4; ++nf) {
                int nc = wn * 64 + nf * 16 + (lane & 15);
                bfr[nf] = *(const bf16x8*)(Bs + nc * 256 + (cbase ^ ((nc & 7) << 4)));
            }
            #pragma unroll
            for (int mf = 0; mf < 4; ++mf)
                #pragma unroll
                for (int nf = 0; nf < 4; ++nf)
                    acc[mf][nf] = __builtin_amdgcn_mfma_f32_16x16x32_bf16(
                        af[ks][mf], bfr[nf], acc[mf][nf], 0, 0, 0);
        }
        __syncthreads();  // all waves done reading Bs
        if (mat < 3) {    // stage next mat's B while we write out
            const char* gB = (const char*)wt + (mat + 1) * 32768;
            #pragma unroll
            for (int i = 0; i < 8; ++i) {
                int chunk = wv * 8 + i;
                gload_lds16(gB + chunk * 1024 + lane * 16, Bs + chunk * 1024);
            }
        }
        __half* base = (mat == 0) ? qb : (mat == 1) ? kv : (mat == 2) ? (kv + 128) : sb;
        const int rs = (mat == 1 || mat == 2) ? 256 : 128;
        const int colbase = wn * 64 + (lane & 15);
        #pragma unroll
        for (int mf = 0; mf < 4; ++mf) {
            int rowb = m0 + wm * 64 + mf * 16 + ((lane >> 4) << 2);
            #pragma unroll
            for (int nf = 0; nf < 4; ++nf) {
                int col = colbase + nf * 16;
                #pragma unroll
                for (int r = 0; r < 4; ++r) {
                    int node = rowb + r;
                    if (node < N_NODES)
                        base[(size_t)node * rs + col] = __float2half_rn(acc[mf][nf][r]);
                }
            }
        }
        __syncthreads();  // staged Bs complete before next mat's reads
    }
}

// ---------------- scan3: redundant partial-scan + intra-block scan ----------------
__global__ __launch_bounds__(256) void k_scan3(const int* __restrict__ deg,
                                               const int* __restrict__ part,
                                               int* __restrict__ offs,
                                               int* __restrict__ cursor)
{
    __shared__ int pbuf[256];
    __shared__ int wsum[4];
    const int t = threadIdx.x;
    int pv = (t < SCAN_BLOCKS) ? part[t] : 0;
    pbuf[t] = pv;
    __syncthreads();
    for (int o = 1; o < 256; o <<= 1) {
        int tmp = (t >= o) ? pbuf[t - o] : 0;
        __syncthreads();
        pbuf[t] += tmp;
        __syncthreads();
    }
    const int bbase = (blockIdx.x == 0) ? 0 : pbuf[blockIdx.x - 1];

    const int idx = blockIdx.x * 256 + t;
    const int lane = t & 63, w = t >> 6;
    int v = (idx < N_NODES) ? deg[idx] : 0;
    int inc = v;
    #pragma unroll
    for (int o = 1; o < 64; o <<= 1) {
        int nb = __shfl_up(inc, o);
        if (lane >= o) inc += nb;
    }
    if (lane == 63) wsum[w] = inc;
    __syncthreads();
    int wbase = 0;
    #pragma unroll
    for (int i = 0; i < 4; ++i) if (i < w) wbase += wsum[i];
    int excl = bbase + wbase + inc - v;
    if (idx < N_NODES) {
        offs[idx] = excl;
        cursor[idx] = excl;
    }
    if (idx == 0) offs[N_NODES] = N_EDGES;
}

__global__ __launch_bounds__(256) void k_scatter(
    const int* __restrict__ src, const int* __restrict__ dst,
    int* __restrict__ cursor, int2* __restrict__ csr)
{
    int e = blockIdx.x * 256 + threadIdx.x;  // E exact
    int d = dst[e];
    int p = atomicAdd(&cursor[d], 1);
    csr[p] = make_int2(src[e], e);
}

// ---------------- fused: logits + exp + aggregate + skip + attn norm + node stats ----------------
// One 64-lane wave per dst node; 16 lanes/edge (8 ch/lane), 4 edges per group.
// QK dot via v_dot2_f32_f16; 2-stage pipeline; LDS ex stash; per-node stats out.
#define GRP_COMPUTE(BASE, K0, K1, K2, K3, V0, V1, V2, V3)                     \
    {                                                                         \
        float p = dot8(K0, K1, K2, K3, qh0, qh1, qh2, qh3);                   \
        p += __shfl_xor(p, 1);                                                \
        p += __shfl_xor(p, 2);                                                \
        const float ex = __expf(p * RSQRT_D);                                 \
        dsum += ex;                                                           \
        float2 g0 = __half22float2(V0), g1 = __half22float2(V1),              \
               g2 = __half22float2(V2), g3 = __half22float2(V3);              \
        acc[0] += ex * g0.x; acc[1] += ex * g0.y;                             \
        acc[2] += ex * g1.x; acc[3] += ex * g1.y;                             \
        acc[4] += ex * g2.x; acc[5] += ex * g2.y;                             \
        acc[6] += ex * g3.x; acc[7] += ex * g3.y;                             \
        if ((lane & 3) == 0) {                                                \
            int sl = (BASE) + qtr - begin;                                    \
            if (sl < EX_CAP) exs[nl][sl * 4 + h] = ex;                        \
            else             exc[((size_t)((BASE) + qtr)) * 4 + h] = ex;      \
        }                                                                     \
    }

__global__ __launch_bounds__(256) void k_fused(
    const __half* __restrict__ qb, const __half* __restrict__ kv,
    const __half* __restrict__ sb,
    const int* __restrict__ offs, const int2* __restrict__ csr,
    float* __restrict__ exc, float* __restrict__ attn,
    float* __restrict__ outb, float2* __restrict__ nstat)
{
    __shared__ __align__(16) float exs[4][EX_CAP * 4];  // 8 KB
    const int t = threadIdx.x;
    const int lane = t & 63;
    const int nl = t >> 6;
    const int n = blockIdx.x * 4 + nl;  // grid*4 == N exact
    const int begin = offs[n], end = offs[n + 1];
    const int cl  = lane & 15;   // owns channels [cl*8, cl*8+8)
    const int qtr = lane >> 4;   // edge slot within 4-group
    const int h   = cl >> 2;     // head of this lane's channels

    const h2* qp = (const h2*)(qb + (size_t)n * 128 + cl * 8);
    const h2 qh0 = qp[0], qh1 = qp[1], qh2 = qp[2], qh3 = qp[3];

    float acc[8] = {0.f, 0.f, 0.f, 0.f, 0.f, 0.f, 0.f, 0.f};
    float dsum = 0.f;
    int i = begin;

    if (i + 4 <= end) {
        // preload group 0
        const __half* rC = kv + (size_t)csr[i + qtr].x * 256 + cl * 8;
        h2 kC0 = ((const h2*)rC)[0], kC1 = ((const h2*)rC)[1],
           kC2 = ((const h2*)rC)[2], kC3 = ((const h2*)rC)[3];
        __half2 vC0 = ((const __half2*)rC)[64], vC1 = ((const __half2*)rC)[65],
                vC2 = ((const __half2*)rC)[66], vC3 = ((const __half2*)rC)[67];
        while (i + 8 <= end) {
            const __half* rN = kv + (size_t)csr[i + 4 + qtr].x * 256 + cl * 8;
            h2 kN0 = ((const h2*)rN)[0], kN1 = ((const h2*)rN)[1],
               kN2 = ((const h2*)rN)[2], kN3 = ((const h2*)rN)[3];
            __half2 vN0 = ((const __half2*)rN)[64], vN1 = ((const __half2*)rN)[65],
                    vN2 = ((const __half2*)rN)[66], vN3 = ((const __half2*)rN)[67];
            GRP_COMPUTE(i, kC0, kC1, kC2, kC3, vC0, vC1, vC2, vC3);
            kC0 = kN0; kC1 = kN1; kC2 = kN2; kC3 = kN3;
            vC0 = vN0; vC1 = vN1; vC2 = vN2; vC3 = vN3;
            i += 4;
        }
        GRP_COMPUTE(i, kC0, kC1, kC2, kC3, vC0, vC1, vC2, vC3);
        i += 4;
    }
    if (i < end) {  // guarded tail: 1-3 edges
        const int eIdx = i + qtr;
        const bool act = eIdx < end;
        const __half* rT = kv + (size_t)csr[act ? eIdx : end - 1].x * 256 + cl * 8;
        h2 ka0 = ((const h2*)rT)[0], ka1 = ((const h2*)rT)[1],
           ka2 = ((const h2*)rT)[2], ka3 = ((const h2*)rT)[3];
        __half2 va0 = ((const __half2*)rT)[64], va1 = ((const __half2*)rT)[65],
                va2 = ((const __half2*)rT)[66], va3 = ((const __half2*)rT)[67];
        float p = dot8(ka0, ka1, ka2, ka3, qh0, qh1, qh2, qh3);
        p += __shfl_xor(p, 1);
        p += __shfl_xor(p, 2);
        const float ex = act ? __expf(p * RSQRT_D) : 0.f;
        dsum += ex;
        float2 g0 = __half22float2(va0), g1 = __half22float2(va1),
               g2 = __half22float2(va2), g3 = __half22float2(va3);
        acc[0] += ex * g0.x; acc[1] += ex * g0.y;
        acc[2] += ex * g1.x; acc[3] += ex * g1.y;
        acc[4] += ex * g2.x; acc[5] += ex * g2.y;
        acc[6] += ex * g3.x; acc[7] += ex * g3.y;
        if (((lane & 3) == 0) && act) {
            int sl = eIdx - begin;
            if (sl < EX_CAP) exs[nl][sl * 4 + h] = ex;
            else             exc[(size_t)eIdx * 4 + h] = ex;
        }
    }

    // combine the 4 edge-quarters (lanes l, l+16, l+32, l+48 share channels)
    dsum += __shfl_xor(dsum, 16);
    dsum += __shfl_xor(dsum, 32);
    #pragma unroll
    for (int j = 0; j < 8; ++j) {
        acc[j] += __shfl_xor(acc[j], 16);
        acc[j] += __shfl_xor(acc[j], 32);
    }
    // per-head reciprocal denominators, broadcast to every lane
    const float rd0 = 1.f / (__shfl(dsum, 0)  + 1e-16f);
    const float rd1 = 1.f / (__shfl(dsum, 4)  + 1e-16f);
    const float rd2 = 1.f / (__shfl(dsum, 8)  + 1e-16f);
    const float rd3 = 1.f / (__shfl(dsum, 12) + 1e-16f);

    if (lane < 16) {
        const float rdn = 1.f / (dsum + 1e-16f);
        const __half2* sp = (const __half2*)(sb + (size_t)n * 128 + cl * 8);
        float o[8];
        #pragma unroll
        for (int j = 0; j < 4; ++j) {
            float2 sf = __half22float2(sp[j]);
            o[2*j]   = acc[2*j]   * rdn + sf.x;
            o[2*j+1] = acc[2*j+1] * rdn + sf.y;
        }
        *(float4*)&outb[(size_t)n * 128 + cl * 8]     = make_float4(o[0], o[1], o[2], o[3]);
        *(float4*)&outb[(size_t)n * 128 + cl * 8 + 4] = make_float4(o[4], o[5], o[6], o[7]);
        // per-node sum / sumsq for the graph-LN stats (lanes 0-15 reduce)
        float lsum = o[0]+o[1]+o[2]+o[3]+o[4]+o[5]+o[6]+o[7];
        float lsq  = o[0]*o[0]+o[1]*o[1]+o[2]*o[2]+o[3]*o[3]
                   + o[4]*o[4]+o[5]*o[5]+o[6]*o[6]+o[7]*o[7];
        lsum += __shfl_xor(lsum, 1); lsq += __shfl_xor(lsq, 1);
        lsum += __shfl_xor(lsum, 2); lsq += __shfl_xor(lsq, 2);
        lsum += __shfl_xor(lsum, 4); lsq += __shfl_xor(lsq, 4);
        lsum += __shfl_xor(lsum, 8); lsq += __shfl_xor(lsq, 8);
        if (lane == 0) nstat[n] = make_float2(lsum, lsq);
    }

    __builtin_amdgcn_sched_barrier(0);  // keep LDS stash writes before epilogue reads

    // normalize this node's attn slots: 1 edge/lane, gathered 16B random write
    for (int slot = begin + lane; slot < end; slot += 64) {
        const int eid = csr[slot].y;
        const int sl = slot - begin;
        float4 e4 = (sl < EX_CAP) ? *(const float4*)&exs[nl][sl * 4]
                                  : *(const float4*)&exc[(size_t)slot * 4];
        ((float4*)attn)[eid] = make_float4(e4.x * rd0, e4.y * rd1,
                                           e4.z * rd2, e4.w * rd3);
    }
}

// ---------------- per-graph stats from per-node stats (600 KB read) ----------------
__global__ __launch_bounds__(256) void k_stats(
    const float2* __restrict__ nstat, const int* __restrict__ batch,
    float* __restrict__ gsum, float* __restrict__ gsq, int* __restrict__ gcnt)
{
    __shared__ float ss[256], qq[256];
    __shared__ int   gg[256];
    const int t = threadIdx.x;
    const int n = blockIdx.x * 256 + t;
    float2 st = (n < N_NODES) ? nstat[n] : make_float2(0.f, 0.f);
    ss[t] = st.x; qq[t] = st.y; gg[t] = (n < N_NODES) ? batch[n] : -1;
    __syncthreads();
    if (t == 0) {  // batch sorted -> 1-2 runs per 256-node block
        float acc = 0.f, accq = 0.f; int cg = gg[0], cnt = 0;
        for (int i = 0; i < 256; ++i) {
            int g = gg[i];
            if (g != cg) {
                if (cg >= 0) { atomicAdd(&gsum[cg], acc); atomicAdd(&gsq[cg], accq);
                               atomicAdd(&gcnt[cg], cnt); }
                acc = 0.f; accq = 0.f; cnt = 0; cg = g;
            }
            acc += ss[i]; accq += qq[i]; ++cnt;
        }
        if (cg >= 0) { atomicAdd(&gsum[cg], acc); atomicAdd(&gsq[cg], accq);
                       atomicAdd(&gcnt[cg], cnt); }
    }
}

// ---------------- LayerNorm affine + LeakyReLU, float4 (in-place) ----------------
__global__ __launch_bounds__(256) void k_final(
    const float* __restrict__ out, const int* __restrict__ batch,
    const float* __restrict__ gsum, const float* __restrict__ gsq,
    const int* __restrict__ gcnt,
    const float* __restrict__ lnw, const float* __restrict__ lnb,
    float* __restrict__ y)
{
    int idx = blockIdx.x * 256 + threadIdx.x;  // Y_SIZE/4 exact
    int n = idx >> 5, c4 = idx & 31;
    int g = batch[n];
    float norm = fmaxf((float)gcnt[g], 1.f) * 128.f;
    float mean = gsum[g] / norm;
    float var  = gsq[g] / norm - mean * mean;
    float inv  = rsqrtf(var + 1e-5f);
    float4 o = *(const float4*)&out[(size_t)idx * 4];
    float4 w = *(const float4*)&lnw[c4 * 4];
    float4 b = *(const float4*)&lnb[c4 * 4];
    float4 r;
    r.x = (o.x - mean) * inv * w.x + b.x;
    r.y = (o.y - mean) * inv * w.y + b.y;
    r.z = (o.z - mean) * inv * w.z + b.z;
    r.w = (o.w - mean) * inv * w.w + b.w;
    r.x = r.x > 0.f ? r.x : 0.01f * r.x;
    r.y = r.y > 0.f ? r.y : 0.01f * r.y;
    r.z = r.z > 0.f ? r.z : 0.01f * r.z;
    r.w = r.w > 0.f ? r.w : 0.01f * r.w;
    *(float4*)&y[(size_t)idx * 4] = r;
}

extern "C" void kernel_launch(void* const* d_in, const int* in_sizes, int n_in,
                              void* d_out, int out_size, void* d_ws, size_t ws_size,
                              hipStream_t stream)
{
    (void)in_sizes; (void)n_in; (void)out_size; (void)ws_size;
    const float* x    = (const float*)d_in[0];
    const int*   ei   = (const int*)  d_in[1];
    const int*   batch= (const int*)  d_in[2];
    const float* Wq   = (const float*)d_in[3];
    const float* bq   = (const float*)d_in[4];
    const float* Wk   = (const float*)d_in[5];
    const float* bk   = (const float*)d_in[6];
    const float* Wv   = (const float*)d_in[7];
    const float* bv   = (const float*)d_in[8];
    const float* Wsm  = (const float*)d_in[9];
    const float* bs   = (const float*)d_in[10];
    const float* lnw  = (const float*)d_in[11];
    const float* lnb  = (const float*)d_in[12];

    float* outp = (float*)d_out;
    float* ws   = (float*)d_ws;

    const int* srcI = ei;
    const int* dstI = ei + N_EDGES;

    __half* qb      = (__half*)(ws + OFF_Q);
    __half* kv      = (__half*)(ws + OFF_K);
    __half* sb      = (__half*)(ws + OFF_S);
    float*  exc     = ws + OFF_EXC;
    short*  wt      = (short*)(ws + OFF_WT);
    float*  gsum    = ws + OFF_GSUM;
    float*  gsq     = ws + OFF_GSQ;
    int*    gcnt    = (int*)(ws + OFF_GCNT);
    int*    deg     = (int*)(ws + OFF_DEG);
    int*    offs    = (int*)(ws + OFF_OFFS);
    int*    cursor  = (int*)(ws + OFF_CURSOR);
    int2*   csr     = (int2*)(ws + OFF_CSR);
    int*    partArr = (int*)(ws + OFF_PART);
    float2* nstat   = (float2*)(ws + OFF_NSTAT);

    float* outb  = outp;                  // y region: x_swz first, then pre-LN out
    short* x_swz = (short*)outp;          // 12.8 MB, dead once k_mmscan finishes
    float* attn  = outp + Y_SIZE;

    // zero gsum/gsq/gcnt + deg (contiguous)
    hipMemsetAsync(gsum, 0, (size_t)(192 + N_NODES) * sizeof(float), stream);

    k_prep<<<XCVT_BLOCKS + 32 + HIST_BLOCKS, 256, 0, stream>>>(
        x, Wq, Wk, Wv, Wsm, dstI, x_swz, wt, deg);
    k_mmscan<<<MM_BLOCKS + SCAN_BLOCKS, 256, 0, stream>>>(
        x_swz, wt, bq, bk, bv, bs, qb, kv, sb, deg, partArr);
    k_scan3<<<SCAN_BLOCKS, 256, 0, stream>>>(deg, partArr, offs, cursor);
    k_scatter<<<N_EDGES / 256, 256, 0, stream>>>(srcI, dstI, cursor, csr);
    k_fused<<<N_NODES / 4, 256, 0, stream>>>(qb, kv, sb, offs, csr,
                                             exc, attn, outb, nstat);
    k_stats<<<SCAN_BLOCKS, 256, 0, stream>>>(nstat, batch, gsum, gsq, gcnt);
    k_final<<<Y_SIZE / 4 / 256, 256, 0, stream>>>(outb, batch, gsum, gsq, gcnt,
                                                  lnw, lnb, outp);
}

// Round 14
// 218.633 us; speedup vs baseline: 1.0430x; 1.0263x over previous
//
#include <hip/hip_runtime.h>
#include <hip/hip_fp16.h>

constexpr int N_NODES = 50000;
constexpr int N_EDGES = 800000;
constexpr int HIDDEN  = 128;
constexpr float RSQRT_D = 0.17677669529663687f;  // 1/sqrt(32)
constexpr int Y_SIZE = N_NODES * HIDDEN;         // 6,400,000
constexpr int M_PAD  = 50048;                    // 782 * 64
constexpr int MM_BLOCKS = M_PAD / 64;            // 782 (64-row tiles, 3 blocks/CU at 48KB LDS)
constexpr int SCAN_BLOCKS = 196;                 // 196*256 = 50176 >= N_NODES
constexpr int XCVT_BLOCKS = (M_PAD * 16) / 256;  // 3128
constexpr int HIST_BLOCKS = N_EDGES / 256;       // 3125
constexpr int EX_CAP = 128;                      // per-node LDS ex slots (deg>128 -> global)

// ---- ws layout (float offsets) ----
constexpr size_t OFF_Q      = 0;         // fp16 qb
constexpr size_t OFF_K      = 6400000;   // fp16 kv interleaved [node][256]: 25.6 MB
constexpr size_t OFF_S      = 19200000;  // fp16 sb
constexpr size_t OFF_EXC    = 22400000;  // E*4 floats: overflow fallback only
constexpr size_t OFF_WT     = 25600000;  // Wt_swz bf16 (dead after k_mm)
constexpr size_t OFF_GSUM   = 25800000;  // 64
constexpr size_t OFF_GSQ    = 25800064;  // 64
constexpr size_t OFF_GCNT   = 25800128;  // 64 ints
constexpr size_t OFF_DEG    = 25800192;  // 50000 ints
constexpr size_t OFF_OFFS   = 25850192;  // 50001 ints
constexpr size_t OFF_CURSOR = 25900224;  // 50000 ints
constexpr size_t OFF_CSR    = 25950224;  // 800000 int2 (packed src,eid)
constexpr size_t OFF_PART   = 27550224;  // 196 ints (raw scan partials)
constexpr size_t OFF_NSTAT  = 27550420;  // 50000 float2 (per-node sum, sumsq)

typedef __attribute__((ext_vector_type(8))) short bf16x8;
typedef __attribute__((ext_vector_type(4))) float f32x4;
typedef __attribute__((ext_vector_type(2))) _Float16 h2;

#if defined(__has_builtin)
# if __has_builtin(__builtin_amdgcn_fdot2)
#  define HAS_FDOT2 1
# endif
#endif

__device__ __forceinline__ float dot8(h2 a0, h2 a1, h2 a2, h2 a3,
                                      h2 b0, h2 b1, h2 b2, h2 b3)
{
#ifdef HAS_FDOT2
    float p = __builtin_amdgcn_fdot2(a0, b0, 0.f, false);
    p = __builtin_amdgcn_fdot2(a1, b1, p, false);
    p = __builtin_amdgcn_fdot2(a2, b2, p, false);
    p = __builtin_amdgcn_fdot2(a3, b3, p, false);
    return p;
#else
    float p = 0.f;
    p += (float)a0.x * (float)b0.x + (float)a0.y * (float)b0.y;
    p += (float)a1.x * (float)b1.x + (float)a1.y * (float)b1.y;
    p += (float)a2.x * (float)b2.x + (float)a2.y * (float)b2.y;
    p += (float)a3.x * (float)b3.x + (float)a3.y * (float)b3.y;
    return p;
#endif
}

__device__ __forceinline__ short f2bf(float f) {  // RNE f32 -> bf16 bits
    unsigned u = __float_as_uint(f);
    unsigned r = (u + 0x7fff + ((u >> 16) & 1)) >> 16;
    return (short)r;
}

__device__ __forceinline__ void gload_lds16(const void* g, void* l) {
    __builtin_amdgcn_global_load_lds(
        (const __attribute__((address_space(1))) void*)g,
        (__attribute__((address_space(3))) void*)l, 16, 0, 0);
}

// ---------------- prep: x->bf16 swizzled | W->Wt bf16 swizzled | degree hist ----------------
__global__ __launch_bounds__(256) void k_prep(
    const float* __restrict__ x,
    const float* __restrict__ Wq, const float* __restrict__ Wk,
    const float* __restrict__ Wv, const float* __restrict__ Wsm,
    const int* __restrict__ dst,
    short* __restrict__ xs, short* __restrict__ wt, int* __restrict__ deg)
{
    int b = blockIdx.x;
    if (b < XCVT_BLOCKS) {
        int tid = b * 256 + threadIdx.x;  // M_PAD*16 exact
        int row = tid >> 4, ci = tid & 15;
        short o[8];
        if (row < N_NODES) {
            float4 a = *(const float4*)&x[(size_t)row * 128 + ci * 8];
            float4 bb = *(const float4*)&x[(size_t)row * 128 + ci * 8 + 4];
            o[0] = f2bf(a.x); o[1] = f2bf(a.y); o[2] = f2bf(a.z); o[3] = f2bf(a.w);
            o[4] = f2bf(bb.x); o[5] = f2bf(bb.y); o[6] = f2bf(bb.z); o[7] = f2bf(bb.w);
        } else {
            #pragma unroll
            for (int j = 0; j < 8; ++j) o[j] = 0;
        }
        int cs = ci ^ (row & 7);
        *(int4*)&xs[(size_t)row * 128 + cs * 8] = *(int4*)o;
    } else if (b < XCVT_BLOCKS + 32) {
        int tid = (b - XCVT_BLOCKS) * 256 + threadIdx.x;  // 8192 exact
        int mat = tid >> 11, n = (tid >> 4) & 127, kg = tid & 15;
        const float* W = (mat == 0) ? Wq : (mat == 1) ? Wk : (mat == 2) ? Wv : Wsm;
        short o[8];
        #pragma unroll
        for (int j = 0; j < 8; ++j) o[j] = f2bf(W[(kg * 8 + j) * 128 + n]);
        int cs = kg ^ (n & 7);
        *(int4*)&wt[mat * 16384 + n * 128 + cs * 8] = *(int4*)o;
    } else {
        int e = (b - XCVT_BLOCKS - 32) * 256 + threadIdx.x;  // E exact
        atomicAdd(&deg[dst[e]], 1);
    }
}

// ---------------- merged: MFMA GEMM (64-row tile, 4 mats) | scan phase 1 ----------------
// 782 GEMM blocks, 48KB LDS -> 3 blocks/CU (was 391 blocks = 1.5/CU: half the
// CUs idle, latency-exposed). Wave layout 1x4: each wave 64x32 per mat.
__global__ __launch_bounds__(256) void k_mmscan(
    const short* __restrict__ xs, const short* __restrict__ wt,
    const float* __restrict__ bq, const float* __restrict__ bk,
    const float* __restrict__ bv, const float* __restrict__ bs,
    __half* __restrict__ qb, __half* __restrict__ kv, __half* __restrict__ sb,
    const int* __restrict__ deg, int* __restrict__ part)
{
    if (blockIdx.x >= MM_BLOCKS) {  // ---- scan1 path ----
        const int t = threadIdx.x;
        int idx = (blockIdx.x - MM_BLOCKS) * 256 + t;
        int v = (idx < N_NODES) ? deg[idx] : 0;
        #pragma unroll
        for (int o = 1; o < 64; o <<= 1) v += __shfl_xor(v, o);
        __shared__ int wsum1[4];
        if ((t & 63) == 0) wsum1[t >> 6] = v;
        __syncthreads();
        if (t == 0) part[blockIdx.x - MM_BLOCKS] = wsum1[0] + wsum1[1] + wsum1[2] + wsum1[3];
        return;
    }
    // ---- GEMM path ----
    __shared__ __align__(16) char As[16384];   // 64 rows x 256B
    __shared__ __align__(16) char Bs[32768];   // 128 cols x 256B
    const int t = threadIdx.x, lane = t & 63, wv = t >> 6;
    const int m0 = blockIdx.x * 64;
    const int wn = wv;  // wave covers cols [wn*32, wn*32+32)

    const char* gA = (const char*)xs + (size_t)m0 * 256;
    #pragma unroll
    for (int i = 0; i < 4; ++i) {  // As: 16 chunks of 1KB
        int chunk = wv * 4 + i;
        gload_lds16(gA + chunk * 1024 + lane * 16, As + chunk * 1024);
    }
    #pragma unroll
    for (int i = 0; i < 8; ++i) {  // Bs: 32 chunks of 1KB (mat 0)
        int chunk = wv * 8 + i;
        gload_lds16((const char*)wt + chunk * 1024 + lane * 16, Bs + chunk * 1024);
    }
    __syncthreads();

    bf16x8 af[4][4];  // [ks][mf], same A for all mats
    #pragma unroll
    for (int ks = 0; ks < 4; ++ks) {
        const int cbase = ks * 64 + ((lane >> 4) << 4);
        #pragma unroll
        for (int mf = 0; mf < 4; ++mf) {
            int mr = mf * 16 + (lane & 15);
            af[ks][mf] = *(const bf16x8*)(As + mr * 256 + (cbase ^ ((mr & 7) << 4)));
        }
    }

    const float* Bbs[4] = {bq, bk, bv, bs};
    #pragma unroll
    for (int mat = 0; mat < 4; ++mat) {
        f32x4 acc[4][2];
        #pragma unroll
        for (int nf = 0; nf < 2; ++nf) {
            float bc = Bbs[mat][wn * 32 + nf * 16 + (lane & 15)];
            #pragma unroll
            for (int mf = 0; mf < 4; ++mf) acc[mf][nf] = (f32x4){bc, bc, bc, bc};
        }
        #pragma unroll
        for (int ks = 0; ks < 4; ++ks) {
            bf16x8 bfr[2];
            const int cbase = ks * 64 + ((lane >> 4) << 4);
            #pragma unroll
            for (int nf = 0; nf < 2; ++nf) {
                int nc = wn * 32 + nf * 16 + (lane & 15);
                bfr[nf] = *(const bf16x8*)(Bs + nc * 256 + (cbase ^ ((nc & 7) << 4)));
            }
            #pragma unroll
            for (int mf = 0; mf < 4; ++mf)
                #pragma unroll
                for (int nf = 0; nf < 2; ++nf)
                    acc[mf][nf] = __builtin_amdgcn_mfma_f32_16x16x32_bf16(
                        af[ks][mf], bfr[nf], acc[mf][nf], 0, 0, 0);
        }
        __syncthreads();  // all waves done reading Bs
        if (mat < 3) {    // stage next mat's B while we write out
            const char* gB = (const char*)wt + (mat + 1) * 32768;
            #pragma unroll
            for (int i = 0; i < 8; ++i) {
                int chunk = wv * 8 + i;
                gload_lds16(gB + chunk * 1024 + lane * 16, Bs + chunk * 1024);
            }
        }
        __half* base = (mat == 0) ? qb : (mat == 1) ? kv : (mat == 2) ? (kv + 128) : sb;
        const int rs = (mat == 1 || mat == 2) ? 256 : 128;
        const int colbase = wn * 32 + (lane & 15);
        #pragma unroll
        for (int mf = 0; mf < 4; ++mf) {
            int rowb = m0 + mf * 16 + ((lane >> 4) << 2);
            #pragma unroll
            for (int nf = 0; nf < 2; ++nf) {
                int col = colbase + nf * 16;
                #pragma unroll
                for (int r = 0; r < 4; ++r) {
                    int node = rowb + r;
                    if (node < N_NODES)
                        base[(size_t)node * rs + col] = __float2half_rn(acc[mf][nf][r]);
                }
            }
        }
        __syncthreads();  // staged Bs complete before next mat's reads
    }
}

// ---------------- scan3: redundant partial-scan + intra-block scan ----------------
__global__ __launch_bounds__(256) void k_scan3(const int* __restrict__ deg,
                                               const int* __restrict__ part,
                                               int* __restrict__ offs,
                                               int* __restrict__ cursor)
{
    __shared__ int pbuf[256];
    __shared__ int wsum[4];
    const int t = threadIdx.x;
    int pv = (t < SCAN_BLOCKS) ? part[t] : 0;
    pbuf[t] = pv;
    __syncthreads();
    for (int o = 1; o < 256; o <<= 1) {
        int tmp = (t >= o) ? pbuf[t - o] : 0;
        __syncthreads();
        pbuf[t] += tmp;
        __syncthreads();
    }
    const int bbase = (blockIdx.x == 0) ? 0 : pbuf[blockIdx.x - 1];

    const int idx = blockIdx.x * 256 + t;
    const int lane = t & 63, w = t >> 6;
    int v = (idx < N_NODES) ? deg[idx] : 0;
    int inc = v;
    #pragma unroll
    for (int o = 1; o < 64; o <<= 1) {
        int nb = __shfl_up(inc, o);
        if (lane >= o) inc += nb;
    }
    if (lane == 63) wsum[w] = inc;
    __syncthreads();
    int wbase = 0;
    #pragma unroll
    for (int i = 0; i < 4; ++i) if (i < w) wbase += wsum[i];
    int excl = bbase + wbase + inc - v;
    if (idx < N_NODES) {
        offs[idx] = excl;
        cursor[idx] = excl;
    }
    if (idx == 0) offs[N_NODES] = N_EDGES;
}

__global__ __launch_bounds__(256) void k_scatter(
    const int* __restrict__ src, const int* __restrict__ dst,
    int* __restrict__ cursor, int2* __restrict__ csr)
{
    int e = blockIdx.x * 256 + threadIdx.x;  // E exact
    int d = dst[e];
    int p = atomicAdd(&cursor[d], 1);
    csr[p] = make_int2(src[e], e);
}

// ---------------- fused: logits + exp + aggregate + skip + attn norm + node stats ----------------
#define GRP_COMPUTE(BASE, K0, K1, K2, K3, V0, V1, V2, V3)                     \
    {                                                                         \
        float p = dot8(K0, K1, K2, K3, qh0, qh1, qh2, qh3);                   \
        p += __shfl_xor(p, 1);                                                \
        p += __shfl_xor(p, 2);                                                \
        const float ex = __expf(p * RSQRT_D);                                 \
        dsum += ex;                                                           \
        float2 g0 = __half22float2(V0), g1 = __half22float2(V1),              \
               g2 = __half22float2(V2), g3 = __half22float2(V3);              \
        acc[0] += ex * g0.x; acc[1] += ex * g0.y;                             \
        acc[2] += ex * g1.x; acc[3] += ex * g1.y;                             \
        acc[4] += ex * g2.x; acc[5] += ex * g2.y;                             \
        acc[6] += ex * g3.x; acc[7] += ex * g3.y;                             \
        if ((lane & 3) == 0) {                                                \
            int sl = (BASE) + qtr - begin;                                    \
            if (sl < EX_CAP) exs[nl][sl * 4 + h] = ex;                        \
            else             exc[((size_t)((BASE) + qtr)) * 4 + h] = ex;      \
        }                                                                     \
    }

__global__ __launch_bounds__(256) void k_fused(
    const __half* __restrict__ qb, const __half* __restrict__ kv,
    const __half* __restrict__ sb,
    const int* __restrict__ offs, const int2* __restrict__ csr,
    float* __restrict__ exc, float* __restrict__ attn,
    float* __restrict__ outb, float2* __restrict__ nstat)
{
    __shared__ __align__(16) float exs[4][EX_CAP * 4];  // 8 KB
    const int t = threadIdx.x;
    const int lane = t & 63;
    const int nl = t >> 6;
    const int n = blockIdx.x * 4 + nl;  // grid*4 == N exact
    const int begin = offs[n], end = offs[n + 1];
    const int cl  = lane & 15;   // owns channels [cl*8, cl*8+8)
    const int qtr = lane >> 4;   // edge slot within 4-group
    const int h   = cl >> 2;     // head of this lane's channels

    const h2* qp = (const h2*)(qb + (size_t)n * 128 + cl * 8);
    const h2 qh0 = qp[0], qh1 = qp[1], qh2 = qp[2], qh3 = qp[3];

    float acc[8] = {0.f, 0.f, 0.f, 0.f, 0.f, 0.f, 0.f, 0.f};
    float dsum = 0.f;
    int i = begin;

    if (i + 4 <= end) {
        const __half* rC = kv + (size_t)csr[i + qtr].x * 256 + cl * 8;
        h2 kC0 = ((const h2*)rC)[0], kC1 = ((const h2*)rC)[1],
           kC2 = ((const h2*)rC)[2], kC3 = ((const h2*)rC)[3];
        __half2 vC0 = ((const __half2*)rC)[64], vC1 = ((const __half2*)rC)[65],
                vC2 = ((const __half2*)rC)[66], vC3 = ((const __half2*)rC)[67];
        while (i + 8 <= end) {
            const __half* rN = kv + (size_t)csr[i + 4 + qtr].x * 256 + cl * 8;
            h2 kN0 = ((const h2*)rN)[0], kN1 = ((const h2*)rN)[1],
               kN2 = ((const h2*)rN)[2], kN3 = ((const h2*)rN)[3];
            __half2 vN0 = ((const __half2*)rN)[64], vN1 = ((const __half2*)rN)[65],
                    vN2 = ((const __half2*)rN)[66], vN3 = ((const __half2*)rN)[67];
            GRP_COMPUTE(i, kC0, kC1, kC2, kC3, vC0, vC1, vC2, vC3);
            kC0 = kN0; kC1 = kN1; kC2 = kN2; kC3 = kN3;
            vC0 = vN0; vC1 = vN1; vC2 = vN2; vC3 = vN3;
            i += 4;
        }
        GRP_COMPUTE(i, kC0, kC1, kC2, kC3, vC0, vC1, vC2, vC3);
        i += 4;
    }
    if (i < end) {  // guarded tail: 1-3 edges
        const int eIdx = i + qtr;
        const bool act = eIdx < end;
        const __half* rT = kv + (size_t)csr[act ? eIdx : end - 1].x * 256 + cl * 8;
        h2 ka0 = ((const h2*)rT)[0], ka1 = ((const h2*)rT)[1],
           ka2 = ((const h2*)rT)[2], ka3 = ((const h2*)rT)[3];
        __half2 va0 = ((const __half2*)rT)[64], va1 = ((const __half2*)rT)[65],
                va2 = ((const __half2*)rT)[66], va3 = ((const __half2*)rT)[67];
        float p = dot8(ka0, ka1, ka2, ka3, qh0, qh1, qh2, qh3);
        p += __shfl_xor(p, 1);
        p += __shfl_xor(p, 2);
        const float ex = act ? __expf(p * RSQRT_D) : 0.f;
        dsum += ex;
        float2 g0 = __half22float2(va0), g1 = __half22float2(va1),
               g2 = __half22float2(va2), g3 = __half22float2(va3);
        acc[0] += ex * g0.x; acc[1] += ex * g0.y;
        acc[2] += ex * g1.x; acc[3] += ex * g1.y;
        acc[4] += ex * g2.x; acc[5] += ex * g2.y;
        acc[6] += ex * g3.x; acc[7] += ex * g3.y;
        if (((lane & 3) == 0) && act) {
            int sl = eIdx - begin;
            if (sl < EX_CAP) exs[nl][sl * 4 + h] = ex;
            else             exc[(size_t)eIdx * 4 + h] = ex;
        }
    }

    // combine the 4 edge-quarters (lanes l, l+16, l+32, l+48 share channels)
    dsum += __shfl_xor(dsum, 16);
    dsum += __shfl_xor(dsum, 32);
    #pragma unroll
    for (int j = 0; j < 8; ++j) {
        acc[j] += __shfl_xor(acc[j], 16);
        acc[j] += __shfl_xor(acc[j], 32);
    }
    // per-head reciprocal denominators, broadcast to every lane
    const float rd0 = 1.f / (__shfl(dsum, 0)  + 1e-16f);
    const float rd1 = 1.f / (__shfl(dsum, 4)  + 1e-16f);
    const float rd2 = 1.f / (__shfl(dsum, 8)  + 1e-16f);
    const float rd3 = 1.f / (__shfl(dsum, 12) + 1e-16f);

    if (lane < 16) {
        const float rdn = 1.f / (dsum + 1e-16f);
        const __half2* sp = (const __half2*)(sb + (size_t)n * 128 + cl * 8);
        float o[8];
        #pragma unroll
        for (int j = 0; j < 4; ++j) {
            float2 sf = __half22float2(sp[j]);
            o[2*j]   = acc[2*j]   * rdn + sf.x;
            o[2*j+1] = acc[2*j+1] * rdn + sf.y;
        }
        *(float4*)&outb[(size_t)n * 128 + cl * 8]     = make_float4(o[0], o[1], o[2], o[3]);
        *(float4*)&outb[(size_t)n * 128 + cl * 8 + 4] = make_float4(o[4], o[5], o[6], o[7]);
        float lsum = o[0]+o[1]+o[2]+o[3]+o[4]+o[5]+o[6]+o[7];
        float lsq  = o[0]*o[0]+o[1]*o[1]+o[2]*o[2]+o[3]*o[3]
                   + o[4]*o[4]+o[5]*o[5]+o[6]*o[6]+o[7]*o[7];
        lsum += __shfl_xor(lsum, 1); lsq += __shfl_xor(lsq, 1);
        lsum += __shfl_xor(lsum, 2); lsq += __shfl_xor(lsq, 2);
        lsum += __shfl_xor(lsum, 4); lsq += __shfl_xor(lsq, 4);
        lsum += __shfl_xor(lsum, 8); lsq += __shfl_xor(lsq, 8);
        if (lane == 0) nstat[n] = make_float2(lsum, lsq);
    }

    __builtin_amdgcn_sched_barrier(0);  // keep LDS stash writes before epilogue reads

    // normalize this node's attn slots: 1 edge/lane, gathered 16B random write
    for (int slot = begin + lane; slot < end; slot += 64) {
        const int eid = csr[slot].y;
        const int sl = slot - begin;
        float4 e4 = (sl < EX_CAP) ? *(const float4*)&exs[nl][sl * 4]
                                  : *(const float4*)&exc[(size_t)slot * 4];
        ((float4*)attn)[eid] = make_float4(e4.x * rd0, e4.y * rd1,
                                           e4.z * rd2, e4.w * rd3);
    }
}

// ---------------- per-graph stats from per-node stats (600 KB read) ----------------
__global__ __launch_bounds__(256) void k_stats(
    const float2* __restrict__ nstat, const int* __restrict__ batch,
    float* __restrict__ gsum, float* __restrict__ gsq, int* __restrict__ gcnt)
{
    __shared__ float ss[256], qq[256];
    __shared__ int   gg[256];
    const int t = threadIdx.x;
    const int n = blockIdx.x * 256 + t;
    float2 st = (n < N_NODES) ? nstat[n] : make_float2(0.f, 0.f);
    ss[t] = st.x; qq[t] = st.y; gg[t] = (n < N_NODES) ? batch[n] : -1;
    __syncthreads();
    if (t == 0) {  // batch sorted -> 1-2 runs per 256-node block
        float acc = 0.f, accq = 0.f; int cg = gg[0], cnt = 0;
        for (int i = 0; i < 256; ++i) {
            int g = gg[i];
            if (g != cg) {
                if (cg >= 0) { atomicAdd(&gsum[cg], acc); atomicAdd(&gsq[cg], accq);
                               atomicAdd(&gcnt[cg], cnt); }
                acc = 0.f; accq = 0.f; cnt = 0; cg = g;
            }
            acc += ss[i]; accq += qq[i]; ++cnt;
        }
        if (cg >= 0) { atomicAdd(&gsum[cg], acc); atomicAdd(&gsq[cg], accq);
                       atomicAdd(&gcnt[cg], cnt); }
    }
}

// ---------------- LayerNorm affine + LeakyReLU, float4 (in-place) ----------------
__global__ __launch_bounds__(256) void k_final(
    const float* __restrict__ out, const int* __restrict__ batch,
    const float* __restrict__ gsum, const float* __restrict__ gsq,
    const int* __restrict__ gcnt,
    const float* __restrict__ lnw, const float* __restrict__ lnb,
    float* __restrict__ y)
{
    int idx = blockIdx.x * 256 + threadIdx.x;  // Y_SIZE/4 exact
    int n = idx >> 5, c4 = idx & 31;
    int g = batch[n];
    float norm = fmaxf((float)gcnt[g], 1.f) * 128.f;
    float mean = gsum[g] / norm;
    float var  = gsq[g] / norm - mean * mean;
    float inv  = rsqrtf(var + 1e-5f);
    float4 o = *(const float4*)&out[(size_t)idx * 4];
    float4 w = *(const float4*)&lnw[c4 * 4];
    float4 b = *(const float4*)&lnb[c4 * 4];
    float4 r;
    r.x = (o.x - mean) * inv * w.x + b.x;
    r.y = (o.y - mean) * inv * w.y + b.y;
    r.z = (o.z - mean) * inv * w.z + b.z;
    r.w = (o.w - mean) * inv * w.w + b.w;
    r.x = r.x > 0.f ? r.x : 0.01f * r.x;
    r.y = r.y > 0.f ? r.y : 0.01f * r.y;
    r.z = r.z > 0.f ? r.z : 0.01f * r.z;
    r.w = r.w > 0.f ? r.w : 0.01f * r.w;
    *(float4*)&y[(size_t)idx * 4] = r;
}

extern "C" void kernel_launch(void* const* d_in, const int* in_sizes, int n_in,
                              void* d_out, int out_size, void* d_ws, size_t ws_size,
                              hipStream_t stream)
{
    (void)in_sizes; (void)n_in; (void)out_size; (void)ws_size;
    const float* x    = (const float*)d_in[0];
    const int*   ei   = (const int*)  d_in[1];
    const int*   batch= (const int*)  d_in[2];
    const float* Wq   = (const float*)d_in[3];
    const float* bq   = (const float*)d_in[4];
    const float* Wk   = (const float*)d_in[5];
    const float* bk   = (const float*)d_in[6];
    const float* Wv   = (const float*)d_in[7];
    const float* bv   = (const float*)d_in[8];
    const float* Wsm  = (const float*)d_in[9];
    const float* bs   = (const float*)d_in[10];
    const float* lnw  = (const float*)d_in[11];
    const float* lnb  = (const float*)d_in[12];

    float* outp = (float*)d_out;
    float* ws   = (float*)d_ws;

    const int* srcI = ei;
    const int* dstI = ei + N_EDGES;

    __half* qb      = (__half*)(ws + OFF_Q);
    __half* kv      = (__half*)(ws + OFF_K);
    __half* sb      = (__half*)(ws + OFF_S);
    float*  exc     = ws + OFF_EXC;
    short*  wt      = (short*)(ws + OFF_WT);
    float*  gsum    = ws + OFF_GSUM;
    float*  gsq     = ws + OFF_GSQ;
    int*    gcnt    = (int*)(ws + OFF_GCNT);
    int*    deg     = (int*)(ws + OFF_DEG);
    int*    offs    = (int*)(ws + OFF_OFFS);
    int*    cursor  = (int*)(ws + OFF_CURSOR);
    int2*   csr     = (int2*)(ws + OFF_CSR);
    int*    partArr = (int*)(ws + OFF_PART);
    float2* nstat   = (float2*)(ws + OFF_NSTAT);

    float* outb  = outp;                  // y region: x_swz first, then pre-LN out
    short* x_swz = (short*)outp;          // 12.8 MB, dead once k_mmscan finishes
    float* attn  = outp + Y_SIZE;

    // zero gsum/gsq/gcnt + deg (contiguous)
    hipMemsetAsync(gsum, 0, (size_t)(192 + N_NODES) * sizeof(float), stream);

    k_prep<<<XCVT_BLOCKS + 32 + HIST_BLOCKS, 256, 0, stream>>>(
        x, Wq, Wk, Wv, Wsm, dstI, x_swz, wt, deg);
    k_mmscan<<<MM_BLOCKS + SCAN_BLOCKS, 256, 0, stream>>>(
        x_swz, wt, bq, bk, bv, bs, qb, kv, sb, deg, partArr);
    k_scan3<<<SCAN_BLOCKS, 256, 0, stream>>>(deg, partArr, offs, cursor);
    k_scatter<<<N_EDGES / 256, 256, 0, stream>>>(srcI, dstI, cursor, csr);
    k_fused<<<N_NODES / 4, 256, 0, stream>>>(qb, kv, sb, offs, csr,
                                             exc, attn, outb, nstat);
    k_stats<<<SCAN_BLOCKS, 256, 0, stream>>>(nstat, batch, gsum, gsq, gcnt);
    k_final<<<Y_SIZE / 4 / 256, 256, 0, stream>>>(outb, batch, gsum, gsq, gcnt,
                                                  lnw, lnb, outp);
}